// Round 7
// baseline (333.119 us; speedup 1.0000x reference)
//
#include <hip/hip_runtime.h>
#include <hip/hip_bf16.h>
#include <stdint.h>

#define N_NODES 50000
#define N_EDGES 800000
#define D_H 128
#define D_E 64
#define HID 128

#define MTILE 96
#define SMAX 16
#define N_ETILES ((N_EDGES + MTILE - 1) / MTILE)     // 8334
#define N_EBLK ((N_ETILES + 1) / 2)                  // 4167 (2 tiles/block)

typedef __attribute__((ext_vector_type(8))) short bf16x8;
typedef __attribute__((ext_vector_type(4))) short s16x4;
typedef __attribute__((ext_vector_type(4))) float f32x4;
typedef __attribute__((ext_vector_type(4))) int i32x4;

__device__ __forceinline__ unsigned short f2bf(float x) {
    unsigned int u = __float_as_uint(x);
    u += 0x7FFFu + ((u >> 16) & 1u);   // round-to-nearest-even
    return (unsigned short)(u >> 16);
}

__device__ __forceinline__ bf16x8 pack8(const f32x4 a, const f32x4 b) {
    bf16x8 o = { (short)f2bf(a[0]), (short)f2bf(a[1]), (short)f2bf(a[2]), (short)f2bf(a[3]),
                 (short)f2bf(b[0]), (short)f2bf(b[1]), (short)f2bf(b[2]), (short)f2bf(b[3]) };
    return o;
}

// ---------------- fused prep: gmax zero + Hb/W1t/W2t converts + deg zero ----------------
__global__ void prep_misc(const float* __restrict__ H,
                          const float* __restrict__ W1,
                          const float* __restrict__ W2,
                          unsigned short* __restrict__ Hb,
                          unsigned short* __restrict__ W1t,
                          unsigned short* __restrict__ W2t,
                          int* __restrict__ deg,
                          float* __restrict__ gmax,
                          int nG, int nHb, int nW1, int nW2) {
    const int b = blockIdx.x, t = threadIdx.x;
    if (b < nG) {
        const int i = b * 256 + t;
        ((f32x4*)gmax)[i] = f32x4{0.f, 0.f, 0.f, 0.f};
    } else if (b < nG + nHb) {
        const int i = (b - nG) * 256 + t;
        const f32x4 v = ((const f32x4*)H)[i];
        s16x4 pkv = { (short)f2bf(v[0]), (short)f2bf(v[1]),
                      (short)f2bf(v[2]), (short)f2bf(v[3]) };
        ((s16x4*)Hb)[i] = pkv;
    } else if (b < nG + nHb + nW1) {                  // W1 -> W1t [128][192] bf16
        const int j = (b - nG - nHb) * 256 + t;
        const int n = j / 192, k = j - n * 192;
        W1t[j] = f2bf(W1[k * HID + n]);
    } else if (b < nG + nHb + nW1 + nW2) {            // W2 -> W2t [128][256] bf16
        const int j = (b - nG - nHb - nW1) * 256 + t;
        const int n = j >> 8, k = j & 255;
        W2t[j] = f2bf(W2[k * HID + n]);
    } else {
        const int j = (b - nG - nHb - nW1 - nW2) * 256 + t;
        if (j < N_NODES / 4) ((i32x4*)deg)[j] = i32x4{0, 0, 0, 0};
    }
}

// ---------------- histogram (4 edges/thread, vectorized read) ----------------
__global__ void hist(const int* __restrict__ idx, int* __restrict__ deg) {
    const int i = blockIdx.x * blockDim.x + threadIdx.x;
    if (i < N_EDGES / 4) {
        const i32x4 d4 = ((const i32x4*)(idx + N_EDGES))[i];
        atomicAdd(&deg[d4.x], 1);
        atomicAdd(&deg[d4.y], 1);
        atomicAdd(&deg[d4.z], 1);
        atomicAdd(&deg[d4.w], 1);
    }
}

// ---------------- single-block exclusive scan, in-place (deg -> cursor) ----------------
#define SCAN_T 1024
#define PER_T 49
__global__ void scan_one(int* __restrict__ deg) {
    __shared__ int s[SCAN_T];
    const int t = threadIdx.x;
    const int beg = t * PER_T;
    const int end = (beg + PER_T < N_NODES) ? beg + PER_T : N_NODES;
    int sum = 0;
    for (int i = beg; i < end; ++i) sum += deg[i];
    s[t] = sum;
    __syncthreads();
    for (int o = 1; o < SCAN_T; o <<= 1) {
        int v = (t >= o) ? s[t - o] : 0;
        __syncthreads();
        s[t] += v;
        __syncthreads();
    }
    int run = t ? s[t - 1] : 0;
    for (int i = beg; i < end; ++i) { const int dv = deg[i]; deg[i] = run; run += dv; }
}

// ---------------- scatter: one packed 8B store per edge ----------------
__global__ void scatter(const int* __restrict__ idx, int* __restrict__ cursor,
                        unsigned long long* __restrict__ pk8) {
    int i = blockIdx.x * blockDim.x + threadIdx.x;
    const int s = idx[i];
    const int d = idx[N_EDGES + i];
    const int p = atomicAdd(&cursor[d], 1);
    pk8[p] = (unsigned long long)(unsigned)i |
             ((unsigned long long)(unsigned)s << 20) |
             ((unsigned long long)(unsigned)d << 37);
}

// ---------------- edge MLP: 2 register-pipelined 96-edge tiles per block ----------------
__global__ __launch_bounds__(256, 3)
void edge_sorted(const float* __restrict__ H,
                 const unsigned short* __restrict__ Hb,
                 const float* __restrict__ Xe,
                 const float* __restrict__ W1,
                 const unsigned short* __restrict__ W1t,
                 const unsigned long long* __restrict__ pk8,
                 float* __restrict__ gmax, int useAux) {
    __shared__ unsigned short sX[MTILE][200];        // 38.4 KB
    __shared__ float ymax[SMAX][132];                // 8.45 KB
    __shared__ int sSrc[2 * MTILE], sE[2 * MTILE], rowD[2 * MTILE];
    __shared__ int segNode[2][SMAX];
    __shared__ int sTot[4];
    __shared__ unsigned char rowG[2 * MTILE];

    const int tid  = threadIdx.x;
    const int wave = tid >> 6;
    const int lane = tid & 63;
    const long long p0 = (long long)blockIdx.x * (2 * MTILE);

    const int col  = lane & 15;
    const int kr0  = (lane >> 4) * 8;
    const int arow = lane & 15;
    const int rb   = (lane >> 4) * 4;
    const int cb   = wave * 32 + col;

    // ---- P0: coalesced pk load + unpack + segment flags ----
    int d = 0;
    bool flag = false;
    bool valid = false;
    if (tid < 2 * MTILE) {
        const long long pe = p0 + tid;
        valid = pe < N_EDGES;
        const long long pc = valid ? pe : (N_EDGES - 1);
        const unsigned long long v = pk8[pc];
        const int e = (int)(v & 0xFFFFFull);
        const int s = (int)((v >> 20) & 0x1FFFFull);
        d = (int)(v >> 37);
        sE[tid] = e; sSrc[tid] = s; rowD[tid] = d;
        const int r = (tid < MTILE) ? tid : tid - MTILE;   // row within tile
        int dp = __shfl_up(d, 1);
        if (lane == 0 && valid && r != 0) dp = (int)(pk8[pe - 1] >> 37);
        flag = valid && (r == 0 || d != dp);
    }
    const unsigned long long m = __ballot(flag);
    if (lane == 0) {
        if (wave == 0) sTot[0] = (int)__popcll(m);
        else if (wave == 1) {
            const int lo = (int)__popcll(m & 0xFFFFFFFFull);
            sTot[1] = lo; sTot[2] = (int)__popcll(m) - lo;
        } else if (wave == 2) sTot[3] = (int)__popcll(m);
    }
    for (int i2 = tid; i2 < SMAX * 132; i2 += 256) ((float*)ymax)[i2] = 0.f;
    __syncthreads();                                  // A: pk tables + sTot + ymax

    // ---- P1: per-row segment ids + gather BOTH tiles into registers ----
    if (tid < 2 * MTILE) {
        const unsigned long long le = (lane == 63) ? ~0ull : ((1ull << (lane + 1)) - 1);
        const int pc_ = (int)__popcll(m & le);
        int g;
        if (wave == 0)                    g = pc_ - 1;
        else if (wave == 1 && lane < 32)  g = sTot[0] + pc_ - 1;           // tail of t0
        else if (wave == 1)               g = pc_ - sTot[1] - 1;           // head of t1
        else                              g = sTot[2] + pc_ - 1;           // rest of t1
        rowG[tid] = (unsigned char)(valid ? g : 255);
        if (flag && g < SMAX) segNode[tid >= MTILE][g] = d;
    }

    // B fragments (W1)
    bf16x8 bfrag[6][2];
    if (useAux) {
        #pragma unroll
        for (int ks = 0; ks < 6; ++ks)
            #pragma unroll
            for (int nf = 0; nf < 2; ++nf) {
                const int n = wave * 32 + nf * 16 + col;
                bfrag[ks][nf] = *(const bf16x8*)&W1t[(size_t)n * 192 + ks * 32 + kr0];
            }
    } else {
        #pragma unroll
        for (int ks = 0; ks < 6; ++ks)
            #pragma unroll
            for (int nf = 0; nf < 2; ++nf) {
                const int n  = wave * 32 + nf * 16 + col;
                const int kb = ks * 32 + kr0;
                bf16x8 b;
                #pragma unroll
                for (int f = 0; f < 8; ++f) b[f] = (short)f2bf(W1[(kb + f) * HID + n]);
                bfrag[ks][nf] = b;
            }
    }

    // gathers: t0 then t1, all issued before any consumer
    bf16x8 hb0[6], hb1[6], xe0[3], xe1[3];
    if (useAux) {
        #pragma unroll
        for (int it = 0; it < 6; ++it) {
            const int j = tid + it * 256, row = j >> 4, c8 = (j & 15) * 8;
            hb0[it] = *(const bf16x8*)(Hb + (size_t)sSrc[row] * D_H + c8);
        }
        #pragma unroll
        for (int it = 0; it < 6; ++it) {
            const int j = tid + it * 256, row = j >> 4, c8 = (j & 15) * 8;
            hb1[it] = *(const bf16x8*)(Hb + (size_t)sSrc[MTILE + row] * D_H + c8);
        }
    } else {
        #pragma unroll
        for (int it = 0; it < 6; ++it) {
            const int j = tid + it * 256, row = j >> 4, c8 = (j & 15) * 8;
            const float* p = H + (size_t)sSrc[row] * D_H + c8;
            hb0[it] = pack8(*(const f32x4*)p, *(const f32x4*)(p + 4));
        }
        #pragma unroll
        for (int it = 0; it < 6; ++it) {
            const int j = tid + it * 256, row = j >> 4, c8 = (j & 15) * 8;
            const float* p = H + (size_t)sSrc[MTILE + row] * D_H + c8;
            hb1[it] = pack8(*(const f32x4*)p, *(const f32x4*)(p + 4));
        }
    }
    #pragma unroll
    for (int it = 0; it < 3; ++it) {
        const int j = tid + it * 256, row = j >> 3, c8 = (j & 7) * 8;
        const float* p = Xe + (size_t)sE[row] * D_E + c8;
        xe0[it] = pack8(*(const f32x4*)p, *(const f32x4*)(p + 4));
    }
    #pragma unroll
    for (int it = 0; it < 3; ++it) {
        const int j = tid + it * 256, row = j >> 3, c8 = (j & 7) * 8;
        const float* p = Xe + (size_t)sE[MTILE + row] * D_E + c8;
        xe1[it] = pack8(*(const f32x4*)p, *(const f32x4*)(p + 4));
    }

    // ds_write tile 0
    #pragma unroll
    for (int it = 0; it < 6; ++it) {
        const int j = tid + it * 256, row = j >> 4, c8 = (j & 15) * 8;
        *(bf16x8*)&sX[row][c8] = hb0[it];
    }
    #pragma unroll
    for (int it = 0; it < 3; ++it) {
        const int j = tid + it * 256, row = j >> 3, c8 = (j & 7) * 8;
        *(bf16x8*)&sX[row][128 + c8] = xe0[it];
    }
    __syncthreads();                                  // B: sX(t0) + rowG + segNode

    // ---- compute / reduce / writeout helpers ----
    auto compute_tile = [&](int tt) {
        f32x4 acc[6][2];
        #pragma unroll
        for (int mm = 0; mm < 6; ++mm) {
            acc[mm][0] = f32x4{0.f, 0.f, 0.f, 0.f};
            acc[mm][1] = f32x4{0.f, 0.f, 0.f, 0.f};
        }
        __builtin_amdgcn_s_setprio(1);
        #pragma unroll
        for (int ks = 0; ks < 6; ++ks)
            #pragma unroll
            for (int mm = 0; mm < 6; ++mm) {
                bf16x8 a = *(const bf16x8*)&sX[mm * 16 + arow][ks * 32 + kr0];
                acc[mm][0] = __builtin_amdgcn_mfma_f32_16x16x32_bf16(a, bfrag[ks][0], acc[mm][0], 0, 0, 0);
                acc[mm][1] = __builtin_amdgcn_mfma_f32_16x16x32_bf16(a, bfrag[ks][1], acc[mm][1], 0, 0, 0);
            }
        __builtin_amdgcn_s_setprio(0);

        const int gb = tt * MTILE;
        #pragma unroll
        for (int mm = 0; mm < 6; ++mm) {
            const int r0 = mm * 16 + rb;
            const int g0 = rowG[gb + r0];
            const int g3 = rowG[gb + r0 + 3];
            if (g0 == g3) {
                const float v0 = fmaxf(fmaxf(acc[mm][0][0], acc[mm][0][1]),
                                       fmaxf(acc[mm][0][2], acc[mm][0][3]));
                const float v1 = fmaxf(fmaxf(acc[mm][1][0], acc[mm][1][1]),
                                       fmaxf(acc[mm][1][2], acc[mm][1][3]));
                if (g0 < SMAX) {
                    if (v0 > 0.f) atomicMax((int*)&ymax[g0][cb],      __float_as_int(v0));
                    if (v1 > 0.f) atomicMax((int*)&ymax[g0][cb + 16], __float_as_int(v1));
                } else if (g0 < 255) {
                    float* base = gmax + (size_t)rowD[gb + r0] * HID;
                    if (v0 > 0.f) atomicMax((int*)(base + cb),      __float_as_int(v0));
                    if (v1 > 0.f) atomicMax((int*)(base + cb + 16), __float_as_int(v1));
                }
            } else {
                #pragma unroll
                for (int r = 0; r < 4; ++r) {
                    const int gg = rowG[gb + r0 + r];
                    const float v0 = acc[mm][0][r];
                    const float v1 = acc[mm][1][r];
                    if (gg < SMAX) {
                        if (v0 > 0.f) atomicMax((int*)&ymax[gg][cb],      __float_as_int(v0));
                        if (v1 > 0.f) atomicMax((int*)&ymax[gg][cb + 16], __float_as_int(v1));
                    } else if (gg < 255) {
                        float* base = gmax + (size_t)rowD[gb + r0 + r] * HID;
                        if (v0 > 0.f) atomicMax((int*)(base + cb),      __float_as_int(v0));
                        if (v1 > 0.f) atomicMax((int*)(base + cb + 16), __float_as_int(v1));
                    }
                }
            }
        }
    };

    auto writeout_tile = [&](int tt) {     // fused re-zero of ymax
        const int nSeg = tt ? (sTot[2] + sTot[3]) : (sTot[0] + sTot[1]);
        const int nS = (nSeg < SMAX) ? nSeg : SMAX;
        for (int i2 = tid; i2 < nS * 128; i2 += 256) {
            const int sg = i2 >> 7;
            const int c  = i2 & 127;
            const float v = ymax[sg][c];
            ymax[sg][c] = 0.f;
            float* dst = gmax + (size_t)segNode[tt][sg] * HID + c;
            if (sg == 0 || sg == nSeg - 1) {
                if (v > 0.f) atomicMax((int*)dst, __float_as_int(v));
            } else {
                *dst = v;
            }
        }
    };

    // ---- pipeline ----
    compute_tile(0);
    __syncthreads();                                  // C: ymax(t0) complete
    writeout_tile(0);
    // ds_write tile 1 (prefetched registers)
    #pragma unroll
    for (int it = 0; it < 6; ++it) {
        const int j = tid + it * 256, row = j >> 4, c8 = (j & 15) * 8;
        *(bf16x8*)&sX[row][c8] = hb1[it];
    }
    #pragma unroll
    for (int it = 0; it < 3; ++it) {
        const int j = tid + it * 256, row = j >> 3, c8 = (j & 7) * 8;
        *(bf16x8*)&sX[row][128 + c8] = xe1[it];
    }
    __syncthreads();                                  // D: sX(t1) + ymax zeroed
    compute_tile(1);
    __syncthreads();                                  // E: ymax(t1) complete
    writeout_tile(1);
}

// ---------------- node MLP + residual ----------------
__global__ __launch_bounds__(256, 4)
void node_mlp(const float* __restrict__ H,
              const float* __restrict__ gmax,
              const float* __restrict__ W2,
              const unsigned short* __restrict__ W2t,
              float* __restrict__ out, int useAux) {
    __shared__ unsigned short sA[64][264];

    const int tid  = threadIdx.x;
    const int wave = tid >> 6;
    const int lane = tid & 63;
    const int base = blockIdx.x * 64;

    const int col = lane & 15;
    const int kr0 = (lane >> 4) * 8;
    bf16x8 bfrag[8][2];
    if (useAux) {
        #pragma unroll
        for (int ks = 0; ks < 8; ++ks)
            #pragma unroll
            for (int nf = 0; nf < 2; ++nf) {
                const int n = wave * 32 + nf * 16 + col;
                bfrag[ks][nf] = *(const bf16x8*)&W2t[(size_t)n * 256 + ks * 32 + kr0];
            }
    } else {
        #pragma unroll
        for (int ks = 0; ks < 8; ++ks)
            #pragma unroll
            for (int nf = 0; nf < 2; ++nf) {
                const int n  = wave * 32 + nf * 16 + col;
                const int kb = ks * 32 + kr0;
                bf16x8 b;
                #pragma unroll
                for (int f = 0; f < 8; ++f) b[f] = (short)f2bf(W2[(kb + f) * HID + n]);
                bfrag[ks][nf] = b;
            }
    }

    #pragma unroll
    for (int it = 0; it < 8; ++it) {
        const int i   = tid + it * 256;
        const int row = i >> 5;
        const int c4  = (i & 31) * 4;
        int node = base + row;
        if (node >= N_NODES) node = N_NODES - 1;
        const f32x4 v = *(const f32x4*)(H + (size_t)node * D_H + c4);
        s16x4 pkv = { (short)f2bf(v[0]), (short)f2bf(v[1]),
                      (short)f2bf(v[2]), (short)f2bf(v[3]) };
        *(s16x4*)&sA[row][c4] = pkv;
    }
    #pragma unroll
    for (int it = 0; it < 8; ++it) {
        const int i   = tid + it * 256;
        const int row = i >> 5;
        const int c4  = (i & 31) * 4;
        int node = base + row;
        if (node >= N_NODES) node = N_NODES - 1;
        const f32x4 v = *(const f32x4*)(gmax + (size_t)node * HID + c4);
        s16x4 pkv = { (short)f2bf(v[0]), (short)f2bf(v[1]),
                      (short)f2bf(v[2]), (short)f2bf(v[3]) };
        *(s16x4*)&sA[row][128 + c4] = pkv;
    }
    __syncthreads();

    f32x4 acc[4][2];
    #pragma unroll
    for (int mm = 0; mm < 4; ++mm) {
        acc[mm][0] = f32x4{0.f, 0.f, 0.f, 0.f};
        acc[mm][1] = f32x4{0.f, 0.f, 0.f, 0.f};
    }
    const int arow = lane & 15;
    __builtin_amdgcn_s_setprio(1);
    #pragma unroll
    for (int ks = 0; ks < 8; ++ks)
        #pragma unroll
        for (int mm = 0; mm < 4; ++mm) {
            bf16x8 a = *(const bf16x8*)&sA[mm * 16 + arow][ks * 32 + kr0];
            acc[mm][0] = __builtin_amdgcn_mfma_f32_16x16x32_bf16(a, bfrag[ks][0], acc[mm][0], 0, 0, 0);
            acc[mm][1] = __builtin_amdgcn_mfma_f32_16x16x32_bf16(a, bfrag[ks][1], acc[mm][1], 0, 0, 0);
        }
    __builtin_amdgcn_s_setprio(0);

    const int rb = (lane >> 4) * 4;
    #pragma unroll
    for (int mm = 0; mm < 4; ++mm)
        #pragma unroll
        for (int r = 0; r < 4; ++r) {
            const int node = base + mm * 16 + rb + r;
            if (node < N_NODES) {
                const size_t o = (size_t)node * HID + wave * 32 + col;
                out[o]      = fmaxf(acc[mm][0][r], 0.f) + H[o];
                out[o + 16] = fmaxf(acc[mm][1][r], 0.f) + H[o + 16];
            }
        }
}

extern "C" void kernel_launch(void* const* d_in, const int* in_sizes, int n_in,
                              void* d_out, int out_size, void* d_ws, size_t ws_size,
                              hipStream_t stream) {
    const float* H   = (const float*)d_in[0];
    const int*   idx = (const int*)d_in[1];
    const float* Xe  = (const float*)d_in[2];
    const float* W1  = (const float*)d_in[3];
    const float* W2  = (const float*)d_in[4];
    float* out = (float*)d_out;

    // ---- workspace layout (core 32.2 MB; aux tail -> 45.1 MB)
    char* ws = (char*)d_ws;
    float* gmax  = (float*)(ws);                             // 25,600,000
    int*   deg   = (int*)(ws + 25600000);                    // 200,000 (becomes cursor)
    unsigned long long* pk8 = (unsigned long long*)(ws + 25800192); // 6,400,000
    unsigned short* W1t = (unsigned short*)(ws + 32200192);  // 49,152
    unsigned short* W2t = (unsigned short*)(ws + 32249344);  // 65,536
    unsigned short* Hb  = (unsigned short*)(ws + 32314880);  // 12,800,000
    const int useAux = (ws_size >= (size_t)45114880) ? 1 : 0;

    const int nG  = 6250;
    const int nHb = useAux ? 6250 : 0;
    const int nW1 = useAux ? 96 : 0;
    const int nW2 = useAux ? 128 : 0;
    const int nZ  = 49;
    prep_misc<<<nG + nHb + nW1 + nW2 + nZ, 256, 0, stream>>>(H, W1, W2, Hb, W1t, W2t,
                                                             deg, gmax, nG, nHb, nW1, nW2);
    hist<<<(N_EDGES / 4 + 255) / 256, 256, 0, stream>>>(idx, deg);
    scan_one<<<1, SCAN_T, 0, stream>>>(deg);
    scatter<<<N_EDGES / 256, 256, 0, stream>>>(idx, deg, pk8);
    edge_sorted<<<N_EBLK, 256, 0, stream>>>(H, Hb, Xe, W1, W1t, pk8, gmax, useAux);
    node_mlp<<<(N_NODES + 63) / 64, 256, 0, stream>>>(H, gmax, W2, W2t, out, useAux);
}

// Round 8
// 254.597 us; speedup vs baseline: 1.3084x; 1.3084x over previous
//
#include <hip/hip_runtime.h>
#include <hip/hip_bf16.h>
#include <stdint.h>

#define N_NODES 50000
#define N_EDGES 800000
#define D_H 128
#define D_E 64
#define HID 128

#define MTILE 96
#define SMAX 16
#define N_ETILES ((N_EDGES + MTILE - 1) / MTILE)     // 8334

#define SCAN_B 512
#define N_CHUNKS ((N_NODES + SCAN_B - 1) / SCAN_B)   // 98

typedef __attribute__((ext_vector_type(8))) short bf16x8;
typedef __attribute__((ext_vector_type(4))) short s16x4;
typedef __attribute__((ext_vector_type(4))) float f32x4;
typedef __attribute__((ext_vector_type(4))) int i32x4;

__device__ __forceinline__ unsigned short f2bf(float x) {
    unsigned int u = __float_as_uint(x);
    u += 0x7FFFu + ((u >> 16) & 1u);   // round-to-nearest-even
    return (unsigned short)(u >> 16);
}

__device__ __forceinline__ bf16x8 pack8(const f32x4 a, const f32x4 b) {
    bf16x8 o = { (short)f2bf(a[0]), (short)f2bf(a[1]), (short)f2bf(a[2]), (short)f2bf(a[3]),
                 (short)f2bf(b[0]), (short)f2bf(b[1]), (short)f2bf(b[2]), (short)f2bf(b[3]) };
    return o;
}

// ---------------- zero: gmax (f32) + deg ----------------
#define NG4 (N_NODES * HID / 4)          // 1,600,000 f32x4
#define ND4 (N_NODES / 4)                // 12,500 i32x4
__global__ void zero_ws(float* __restrict__ gmax, int* __restrict__ deg) {
    const int i = blockIdx.x * blockDim.x + threadIdx.x;
    if (i < NG4) {
        ((f32x4*)gmax)[i] = f32x4{0.f, 0.f, 0.f, 0.f};
    } else if (i < NG4 + ND4) {
        ((i32x4*)deg)[i - NG4] = i32x4{0, 0, 0, 0};
    }
}

// ---------------- converts: Hb + W1t + W2t ----------------
#define NHB4 (N_NODES * D_H / 4)         // 1,600,000 s16x4 granules
#define NW1 (192 * HID)                  // 24,576
#define NW2 (256 * HID)                  // 32,768
__global__ void conv_aux(const float* __restrict__ H,
                         const float* __restrict__ W1,
                         const float* __restrict__ W2,
                         unsigned short* __restrict__ Hb,
                         unsigned short* __restrict__ W1t,
                         unsigned short* __restrict__ W2t) {
    const int i = blockIdx.x * blockDim.x + threadIdx.x;
    if (i < NHB4) {
        const f32x4 v = ((const f32x4*)H)[i];
        s16x4 pkv = { (short)f2bf(v[0]), (short)f2bf(v[1]),
                      (short)f2bf(v[2]), (short)f2bf(v[3]) };
        ((s16x4*)Hb)[i] = pkv;
    } else if (i < NHB4 + NW1) {                     // W1t [128][192] bf16
        const int j = i - NHB4;
        const int n = j / 192, k = j - n * 192;
        W1t[j] = f2bf(W1[k * HID + n]);
    } else if (i < NHB4 + NW1 + NW2) {               // W2t [128][256] bf16
        const int j = i - NHB4 - NW1;
        const int n = j >> 8, k = j & 255;
        W2t[j] = f2bf(W2[k * HID + n]);
    }
}

// ---------------- histogram ----------------
__global__ void hist(const int* __restrict__ idx, int* __restrict__ deg) {
    const int i = blockIdx.x * blockDim.x + threadIdx.x;
    atomicAdd(&deg[idx[N_EDGES + i]], 1);
}

// ---------------- 3-kernel parallel exclusive scan ----------------
__global__ void scan_a(const int* __restrict__ deg, int* __restrict__ sc,
                       int* __restrict__ totals) {
    __shared__ int s[SCAN_B];
    const int tid = threadIdx.x;
    const int i = blockIdx.x * SCAN_B + tid;
    const int v = (i < N_NODES) ? deg[i] : 0;
    s[tid] = v;
    __syncthreads();
    for (int o = 1; o < SCAN_B; o <<= 1) {
        int t = (tid >= o) ? s[tid - o] : 0;
        __syncthreads();
        s[tid] += t;
        __syncthreads();
    }
    if (i < N_NODES) sc[i] = s[tid] - v;
    if (tid == SCAN_B - 1) totals[blockIdx.x] = s[SCAN_B - 1];
}

__global__ void scan_b(int* __restrict__ totals) {
    __shared__ int s[128];
    const int tid = threadIdx.x;
    const int v = (tid < N_CHUNKS) ? totals[tid] : 0;
    s[tid] = v;
    __syncthreads();
    for (int o = 1; o < 128; o <<= 1) {
        int t = (tid >= o) ? s[tid - o] : 0;
        __syncthreads();
        s[tid] += t;
        __syncthreads();
    }
    if (tid < N_CHUNKS) totals[tid] = s[tid] - v;
}

__global__ void scan_c(const int* __restrict__ sc, const int* __restrict__ totals,
                       int* __restrict__ cursor) {
    const int i = blockIdx.x * SCAN_B + threadIdx.x;
    if (i < N_NODES) cursor[i] = sc[i] + totals[blockIdx.x];
}

// ---------------- scatter: one packed 8B store per edge ----------------
__global__ void scatter(const int* __restrict__ idx, int* __restrict__ cursor,
                        unsigned long long* __restrict__ pk8) {
    int i = blockIdx.x * blockDim.x + threadIdx.x;
    const int s = idx[i];
    const int d = idx[N_EDGES + i];
    const int p = atomicAdd(&cursor[d], 1);
    pk8[p] = (unsigned long long)(unsigned)i |
             ((unsigned long long)(unsigned)s << 20) |
             ((unsigned long long)(unsigned)d << 37);
}

// ---------------- edge MLP, one 96-edge tile per block (R6 structure) ----------------
__global__ __launch_bounds__(256, 3)
void edge_sorted(const float* __restrict__ H,
                 const unsigned short* __restrict__ Hb,
                 const float* __restrict__ Xe,
                 const float* __restrict__ W1,
                 const unsigned short* __restrict__ W1t,
                 const unsigned long long* __restrict__ pk8,
                 float* __restrict__ gmax, int useAux) {
    __shared__ unsigned short sX[MTILE][200];        // 38.4 KB
    __shared__ float ymax[SMAX + 1][132];            // 9.0 KB
    __shared__ int rowD[MTILE];
    __shared__ int segNode[SMAX];
    __shared__ int sWaveTot[4];
    __shared__ unsigned char rowG[MTILE];

    const int tid  = threadIdx.x;
    const int wave = tid >> 6;
    const int lane = tid & 63;
    const int p0   = blockIdx.x * MTILE;

    const int col = lane & 15;
    const int kr0 = (lane >> 4) * 8;

    // --- stage issues first: all gather loads go out before any barrier ---
    if (useAux) {
        #pragma unroll
        for (int it = 0; it < 6; ++it) {
            const int j   = tid + it * 256;          // < 1536
            const int row = j >> 4;
            const int c8  = (j & 15) * 8;
            int pe = p0 + row; if (pe >= N_EDGES) pe = N_EDGES - 1;
            const int src = (int)((pk8[pe] >> 20) & 0x1FFFFull);
            *(bf16x8*)&sX[row][c8] = *(const bf16x8*)(Hb + (size_t)src * D_H + c8);
        }
    } else {
        #pragma unroll
        for (int it = 0; it < 12; ++it) {
            const int j   = tid + it * 256;          // < 3072
            const int row = j >> 5;
            const int c4  = (j & 31) * 4;
            int pe = p0 + row; if (pe >= N_EDGES) pe = N_EDGES - 1;
            const int src = (int)((pk8[pe] >> 20) & 0x1FFFFull);
            const f32x4 v = *(const f32x4*)(H + (size_t)src * D_H + c4);
            s16x4 pkv = { (short)f2bf(v[0]), (short)f2bf(v[1]),
                          (short)f2bf(v[2]), (short)f2bf(v[3]) };
            *(s16x4*)&sX[row][c4] = pkv;
        }
    }
    #pragma unroll
    for (int it = 0; it < 3; ++it) {
        const int j   = tid + it * 256;              // < 768
        const int row = j >> 3;
        const int c8  = (j & 7) * 8;
        int pe = p0 + row; if (pe >= N_EDGES) pe = N_EDGES - 1;
        const int e = (int)(pk8[pe] & 0xFFFFFull);
        const float* p = Xe + (size_t)e * D_E + c8;
        *(bf16x8*)&sX[row][128 + c8] = pack8(*(const f32x4*)p, *(const f32x4*)(p + 4));
    }

    // --- B fragments (W1), wave covers cols [wave*32, wave*32+32)
    bf16x8 bfrag[6][2];
    if (useAux) {
        #pragma unroll
        for (int ks = 0; ks < 6; ++ks)
            #pragma unroll
            for (int nf = 0; nf < 2; ++nf) {
                const int n = wave * 32 + nf * 16 + col;
                bfrag[ks][nf] = *(const bf16x8*)&W1t[(size_t)n * 192 + ks * 32 + kr0];
            }
    } else {
        #pragma unroll
        for (int ks = 0; ks < 6; ++ks)
            #pragma unroll
            for (int nf = 0; nf < 2; ++nf) {
                const int n  = wave * 32 + nf * 16 + col;
                const int kb = ks * 32 + kr0;
                bf16x8 b;
                #pragma unroll
                for (int f = 0; f < 8; ++f) b[f] = (short)f2bf(W1[(kb + f) * HID + n]);
                bfrag[ks][nf] = b;
            }
    }

    // --- tile-local segmentation ---
    const int pe0 = p0 + tid;
    const bool inTile = (tid < MTILE);
    const bool valid  = inTile && (pe0 < N_EDGES);
    int d = 0;
    if (inTile) {
        const int pc = valid ? pe0 : (N_EDGES - 1);
        d = (int)(pk8[pc] >> 37);
        rowD[tid] = d;
    }
    int dp = __shfl_up(d, 1);
    if (lane == 0 && inTile && tid > 0) dp = (int)(pk8[pe0 - 1] >> 37);
    const bool flag = valid && (tid == 0 || d != dp);
    const unsigned long long m = __ballot(flag);
    if (lane == 0) sWaveTot[wave] = (int)__popcll(m);

    for (int i2 = tid; i2 < (SMAX + 1) * 132; i2 += 256) ((float*)ymax)[i2] = 0.f;
    __syncthreads();                                  // A: sWaveTot ready

    int g = 255;
    if (valid) {
        const unsigned long long le =
            (lane == 63) ? ~0ull : ((1ull << (lane + 1)) - 1);
        g = (int)__popcll(m & le) - 1 + ((wave == 1) ? sWaveTot[0] : 0);
    }
    if (inTile) rowG[tid] = (unsigned char)(valid ? g : 255);
    if (flag && g < SMAX) segNode[g] = d;
    __syncthreads();                                  // B: sX + rowG + segNode ready

    // --- MFMA: 96 x 192 @ 192 x 32 per wave
    f32x4 acc[6][2];
    #pragma unroll
    for (int mm = 0; mm < 6; ++mm) {
        acc[mm][0] = f32x4{0.f, 0.f, 0.f, 0.f};
        acc[mm][1] = f32x4{0.f, 0.f, 0.f, 0.f};
    }
    const int arow = lane & 15;
    __builtin_amdgcn_s_setprio(1);
    #pragma unroll
    for (int ks = 0; ks < 6; ++ks)
        #pragma unroll
        for (int mm = 0; mm < 6; ++mm) {
            bf16x8 a = *(const bf16x8*)&sX[mm * 16 + arow][ks * 32 + kr0];
            acc[mm][0] = __builtin_amdgcn_mfma_f32_16x16x32_bf16(a, bfrag[ks][0], acc[mm][0], 0, 0, 0);
            acc[mm][1] = __builtin_amdgcn_mfma_f32_16x16x32_bf16(a, bfrag[ks][1], acc[mm][1], 0, 0, 0);
        }
    __builtin_amdgcn_s_setprio(0);

    // --- relu + segmented max into LDS (overflow segs -> direct global atomics)
    const int rb = (lane >> 4) * 4;
    const int cb = wave * 32 + col;
    #pragma unroll
    for (int mm = 0; mm < 6; ++mm) {
        const int r0 = mm * 16 + rb;
        const int g0 = rowG[r0];
        const int g3 = rowG[r0 + 3];
        if (g0 == g3) {
            const float v0 = fmaxf(fmaxf(acc[mm][0][0], acc[mm][0][1]),
                                   fmaxf(acc[mm][0][2], acc[mm][0][3]));
            const float v1 = fmaxf(fmaxf(acc[mm][1][0], acc[mm][1][1]),
                                   fmaxf(acc[mm][1][2], acc[mm][1][3]));
            if (g0 < SMAX) {
                if (v0 > 0.f) atomicMax((int*)&ymax[g0][cb],      __float_as_int(v0));
                if (v1 > 0.f) atomicMax((int*)&ymax[g0][cb + 16], __float_as_int(v1));
            } else if (g0 < 255) {
                float* base = gmax + (size_t)rowD[r0] * HID;
                if (v0 > 0.f) atomicMax((int*)(base + cb),      __float_as_int(v0));
                if (v1 > 0.f) atomicMax((int*)(base + cb + 16), __float_as_int(v1));
            }
        } else {
            #pragma unroll
            for (int r = 0; r < 4; ++r) {
                const int gg = rowG[r0 + r];
                const float v0 = acc[mm][0][r];
                const float v1 = acc[mm][1][r];
                if (gg < SMAX) {
                    if (v0 > 0.f) atomicMax((int*)&ymax[gg][cb],      __float_as_int(v0));
                    if (v1 > 0.f) atomicMax((int*)&ymax[gg][cb + 16], __float_as_int(v1));
                } else if (gg < 255) {
                    float* base = gmax + (size_t)rowD[r0 + r] * HID;
                    if (v0 > 0.f) atomicMax((int*)(base + cb),      __float_as_int(v0));
                    if (v1 > 0.f) atomicMax((int*)(base + cb + 16), __float_as_int(v1));
                }
            }
        }
    }
    __syncthreads();                                  // C: ymax ready

    // --- writeout: interior segments plain store, first/last atomicMax
    const int nSeg = sWaveTot[0] + sWaveTot[1];
    const int nS = (nSeg < SMAX) ? nSeg : SMAX;
    for (int i2 = tid; i2 < nS * 128; i2 += 256) {
        const int sg = i2 >> 7;
        const int c  = i2 & 127;
        const float v = ymax[sg][c];
        float* dst = gmax + (size_t)segNode[sg] * HID + c;
        if (sg == 0 || sg == nSeg - 1) {
            if (v > 0.f) atomicMax((int*)dst, __float_as_int(v));
        } else {
            *dst = v;
        }
    }
}

// ---------------- node MLP + residual ----------------
__global__ __launch_bounds__(256, 4)
void node_mlp(const float* __restrict__ H,
              const float* __restrict__ gmax,
              const float* __restrict__ W2,
              const unsigned short* __restrict__ W2t,
              float* __restrict__ out, int useAux) {
    __shared__ unsigned short sA[64][264];

    const int tid  = threadIdx.x;
    const int wave = tid >> 6;
    const int lane = tid & 63;
    const int base = blockIdx.x * 64;

    const int col = lane & 15;
    const int kr0 = (lane >> 4) * 8;
    bf16x8 bfrag[8][2];
    if (useAux) {
        #pragma unroll
        for (int ks = 0; ks < 8; ++ks)
            #pragma unroll
            for (int nf = 0; nf < 2; ++nf) {
                const int n = wave * 32 + nf * 16 + col;
                bfrag[ks][nf] = *(const bf16x8*)&W2t[(size_t)n * 256 + ks * 32 + kr0];
            }
    } else {
        #pragma unroll
        for (int ks = 0; ks < 8; ++ks)
            #pragma unroll
            for (int nf = 0; nf < 2; ++nf) {
                const int n  = wave * 32 + nf * 16 + col;
                const int kb = ks * 32 + kr0;
                bf16x8 b;
                #pragma unroll
                for (int f = 0; f < 8; ++f) b[f] = (short)f2bf(W2[(kb + f) * HID + n]);
                bfrag[ks][nf] = b;
            }
    }

    #pragma unroll
    for (int it = 0; it < 8; ++it) {
        const int i   = tid + it * 256;
        const int row = i >> 5;
        const int c4  = (i & 31) * 4;
        int node = base + row;
        if (node >= N_NODES) node = N_NODES - 1;
        const f32x4 v = *(const f32x4*)(H + (size_t)node * D_H + c4);
        s16x4 pkv = { (short)f2bf(v[0]), (short)f2bf(v[1]),
                      (short)f2bf(v[2]), (short)f2bf(v[3]) };
        *(s16x4*)&sA[row][c4] = pkv;
    }
    #pragma unroll
    for (int it = 0; it < 8; ++it) {
        const int i   = tid + it * 256;
        const int row = i >> 5;
        const int c4  = (i & 31) * 4;
        int node = base + row;
        if (node >= N_NODES) node = N_NODES - 1;
        const f32x4 v = *(const f32x4*)(gmax + (size_t)node * HID + c4);
        s16x4 pkv = { (short)f2bf(v[0]), (short)f2bf(v[1]),
                      (short)f2bf(v[2]), (short)f2bf(v[3]) };
        *(s16x4*)&sA[row][128 + c4] = pkv;
    }
    __syncthreads();

    f32x4 acc[4][2];
    #pragma unroll
    for (int mm = 0; mm < 4; ++mm) {
        acc[mm][0] = f32x4{0.f, 0.f, 0.f, 0.f};
        acc[mm][1] = f32x4{0.f, 0.f, 0.f, 0.f};
    }
    const int arow = lane & 15;
    __builtin_amdgcn_s_setprio(1);
    #pragma unroll
    for (int ks = 0; ks < 8; ++ks)
        #pragma unroll
        for (int mm = 0; mm < 4; ++mm) {
            bf16x8 a = *(const bf16x8*)&sA[mm * 16 + arow][ks * 32 + kr0];
            acc[mm][0] = __builtin_amdgcn_mfma_f32_16x16x32_bf16(a, bfrag[ks][0], acc[mm][0], 0, 0, 0);
            acc[mm][1] = __builtin_amdgcn_mfma_f32_16x16x32_bf16(a, bfrag[ks][1], acc[mm][1], 0, 0, 0);
        }
    __builtin_amdgcn_s_setprio(0);

    const int rb = (lane >> 4) * 4;
    #pragma unroll
    for (int mm = 0; mm < 4; ++mm)
        #pragma unroll
        for (int r = 0; r < 4; ++r) {
            const int node = base + mm * 16 + rb + r;
            if (node < N_NODES) {
                const size_t o = (size_t)node * HID + wave * 32 + col;
                out[o]      = fmaxf(acc[mm][0][r], 0.f) + H[o];
                out[o + 16] = fmaxf(acc[mm][1][r], 0.f) + H[o + 16];
            }
        }
}

extern "C" void kernel_launch(void* const* d_in, const int* in_sizes, int n_in,
                              void* d_out, int out_size, void* d_ws, size_t ws_size,
                              hipStream_t stream) {
    const float* H   = (const float*)d_in[0];
    const int*   idx = (const int*)d_in[1];
    const float* Xe  = (const float*)d_in[2];
    const float* W1  = (const float*)d_in[3];
    const float* W2  = (const float*)d_in[4];
    float* out = (float*)d_out;

    // ---- workspace layout (core 32.4 MB; aux tail -> 45.3 MB)
    char* ws = (char*)d_ws;
    float* gmax   = (float*)(ws);                            // 25,600,000
    int*   deg    = (int*)(ws + 25600000);                   // 200,000 (scan_c -> cursor)
    int*   sc     = (int*)(ws + 25800192);                   // 200,000
    int*   totals = (int*)(ws + 26000384);                   // 512
    unsigned long long* pk8 = (unsigned long long*)(ws + 26000896); // 6,400,000
    unsigned short* W1t = (unsigned short*)(ws + 32400896);  // 49,152
    unsigned short* W2t = (unsigned short*)(ws + 32450048);  // 65,536
    unsigned short* Hb  = (unsigned short*)(ws + 32515584);  // 12,800,000
    const int useAux = (ws_size >= (size_t)45315584) ? 1 : 0;

    zero_ws<<<(NG4 + ND4 + 255) / 256, 256, 0, stream>>>(gmax, deg);
    if (useAux)
        conv_aux<<<(NHB4 + NW1 + NW2 + 255) / 256, 256, 0, stream>>>(H, W1, W2, Hb, W1t, W2t);
    hist<<<N_EDGES / 256, 256, 0, stream>>>(idx, deg);
    scan_a<<<N_CHUNKS, SCAN_B, 0, stream>>>(deg, sc, totals);
    scan_b<<<1, 128, 0, stream>>>(totals);
    scan_c<<<N_CHUNKS, SCAN_B, 0, stream>>>(sc, totals, deg);
    scatter<<<N_EDGES / 256, 256, 0, stream>>>(idx, deg, pk8);
    edge_sorted<<<N_ETILES, 256, 0, stream>>>(H, Hb, Xe, W1, W1t, pk8, gmax, useAux);
    node_mlp<<<(N_NODES + 63) / 64, 256, 0, stream>>>(H, gmax, W2, W2t, out, useAux);
}